// Round 1
// baseline (284.885 us; speedup 1.0000x reference)
//
#include <hip/hip_runtime.h>

// Sparse voxel downsample (FACTOR=2, RES=256 -> res=128, B=2, C=64).
// code = ((b*128 + x/2)*128 + y/2)*128 + z/2  in [0, 4194304)
// Dense histogram + 2-level scan over occupancy flags gives each code its
// sorted rank == jnp.unique inverse index. Then atomic scatter-mean.

#define RES2 128
#define NCODES (2 * 128 * 128 * 128)   // B * res^3 = 4194304
#define SCAN_BLK 4096                  // NCODES / 1024 codes per block

__device__ __forceinline__ int code_of(const int* __restrict__ coords, int i) {
    int b = coords[4 * i + 0];
    int x = coords[4 * i + 1] >> 1;
    int y = coords[4 * i + 2] >> 1;
    int z = coords[4 * i + 3] >> 1;
    return ((b * RES2 + x) * RES2 + y) * RES2 + z;
}

__global__ void count_codes(const int* __restrict__ coords,
                            unsigned* __restrict__ cnt, int n) {
    int i = blockIdx.x * 256 + threadIdx.x;
    if (i >= n) return;
    atomicAdd(&cnt[code_of(coords, i)], 1u);
}

// Per-block (1024 codes) count of occupied codes.
__global__ void block_flag_sum(const unsigned* __restrict__ cnt,
                               unsigned* __restrict__ btot) {
    __shared__ unsigned sh[256];
    int base = blockIdx.x * 1024 + threadIdx.x * 4;
    const uint4 v = *reinterpret_cast<const uint4*>(cnt + base);
    unsigned s = (v.x != 0) + (v.y != 0) + (v.z != 0) + (v.w != 0);
    sh[threadIdx.x] = s;
    __syncthreads();
    for (int off = 128; off > 0; off >>= 1) {
        if (threadIdx.x < off) sh[threadIdx.x] += sh[threadIdx.x + off];
        __syncthreads();
    }
    if (threadIdx.x == 0) btot[blockIdx.x] = sh[0];
}

// Single block: exclusive scan over the 4096 block totals (4 per thread).
__global__ void scan_block_totals(unsigned* __restrict__ btot) {
    __shared__ unsigned sh[1024];
    int t = threadIdx.x;
    int base = t * 4;
    unsigned v[4], e[4], s = 0;
#pragma unroll
    for (int j = 0; j < 4; ++j) { v[j] = btot[base + j]; e[j] = s; s += v[j]; }
    sh[t] = s;
    __syncthreads();
    for (int off = 1; off < 1024; off <<= 1) {
        unsigned add = (t >= off) ? sh[t - off] : 0u;
        __syncthreads();
        sh[t] += add;
        __syncthreads();
    }
    unsigned excl = (t == 0) ? 0u : sh[t - 1];
#pragma unroll
    for (int j = 0; j < 4; ++j) btot[base + j] = excl + e[j];
}

// Second pass over flags: per-block exclusive scan + global base -> sorted
// rank for every occupied code. Writes uniq_code/uniq_cnt and overwrites
// cnt[code] with the rank (codes with cnt==0 are never looked up later).
__global__ void scan_write(unsigned* __restrict__ cnt,
                           const unsigned* __restrict__ btot,
                           int* __restrict__ uniq_code,
                           unsigned* __restrict__ uniq_cnt) {
    __shared__ unsigned sh[256];
    int t = threadIdx.x;
    int base = blockIdx.x * 1024 + t * 4;
    const uint4 v = *reinterpret_cast<const uint4*>(cnt + base);
    unsigned c4[4] = {v.x, v.y, v.z, v.w};
    unsigned e[4], s = 0;
#pragma unroll
    for (int j = 0; j < 4; ++j) { e[j] = s; s += (c4[j] != 0); }
    sh[t] = s;
    __syncthreads();
    for (int off = 1; off < 256; off <<= 1) {
        unsigned add = (t >= off) ? sh[t - off] : 0u;
        __syncthreads();
        sh[t] += add;
        __syncthreads();
    }
    unsigned texcl = ((t == 0) ? 0u : sh[t - 1]) + btot[blockIdx.x];
#pragma unroll
    for (int j = 0; j < 4; ++j) {
        if (c4[j]) {
            unsigned r = texcl + e[j];
            uniq_code[r] = base + j;
            uniq_cnt[r] = c4[j];
            cnt[base + j] = r;   // repurpose as rank table
        }
    }
}

// One thread per (input row, channel): accumulate into output row = rank.
__global__ void scatter_feats(const float* __restrict__ feats,
                              const int* __restrict__ coords,
                              const unsigned* __restrict__ rank,
                              float* __restrict__ outF, int n) {
    int tid = blockIdx.x * 256 + threadIdx.x;
    if (tid >= n * 64) return;
    int i = tid >> 6;
    int c = tid & 63;
    unsigned r = rank[code_of(coords, i)];
    atomicAdd(&outF[(size_t)r * 64 + c], feats[tid]);
}

// One thread per (output row, channel): divide by count; lanes c<4 also
// decode + write coords (as float values; -1 for padding rows).
__global__ void finalize(const int* __restrict__ uniq_code,
                         const unsigned* __restrict__ uniq_cnt,
                         float* __restrict__ outF,
                         float* __restrict__ outC, int n) {
    int tid = blockIdx.x * 256 + threadIdx.x;
    if (tid >= n * 64) return;
    int r = tid >> 6;
    int c = tid & 63;
    unsigned cr = uniq_cnt[r];
    if (cr) {
        outF[tid] = outF[tid] / (float)cr;
        if (c < 4) {
            int code = uniq_code[r];
            int z = code & 127;
            int y = (code >> 7) & 127;
            int x = (code >> 14) & 127;
            int b = code >> 21;
            int val = (c == 0) ? b : (c == 1) ? x : (c == 2) ? y : z;
            outC[(size_t)r * 4 + c] = (float)val;
        }
    } else if (c < 4) {
        outC[(size_t)r * 4 + c] = -1.0f;
    }
}

extern "C" void kernel_launch(void* const* d_in, const int* in_sizes, int n_in,
                              void* d_out, int out_size, void* d_ws, size_t ws_size,
                              hipStream_t stream) {
    const float* feats = (const float*)d_in[0];
    const int* coords = (const int*)d_in[1];
    const int n = in_sizes[1] / 4;   // N = 500000

    float* outF = (float*)d_out;
    float* outC = outF + (size_t)n * 64;

    unsigned* cnt = (unsigned*)d_ws;                 // NCODES u32 (16 MB)
    unsigned* btot = cnt + NCODES;                   // SCAN_BLK u32
    int* uniq_code = (int*)(btot + SCAN_BLK);        // n i32
    unsigned* uniq_cnt = (unsigned*)(uniq_code + n); // n u32

    hipMemsetAsync(d_out, 0, (size_t)out_size * sizeof(float), stream);
    hipMemsetAsync(cnt, 0, (size_t)NCODES * sizeof(unsigned), stream);
    hipMemsetAsync(uniq_cnt, 0, (size_t)n * sizeof(unsigned), stream);

    count_codes<<<(n + 255) / 256, 256, 0, stream>>>(coords, cnt, n);
    block_flag_sum<<<SCAN_BLK, 256, 0, stream>>>(cnt, btot);
    scan_block_totals<<<1, 1024, 0, stream>>>(btot);
    scan_write<<<SCAN_BLK, 256, 0, stream>>>(cnt, btot, uniq_code, uniq_cnt);

    int nc_threads = n * 64;
    scatter_feats<<<(nc_threads + 255) / 256, 256, 0, stream>>>(feats, coords, cnt, outF, n);
    finalize<<<(nc_threads + 255) / 256, 256, 0, stream>>>(uniq_code, uniq_cnt, outF, outC, n);
}

// Round 2
// 280.677 us; speedup vs baseline: 1.0150x; 1.0150x over previous
//
#include <hip/hip_runtime.h>

// Sparse voxel downsample (FACTOR=2, RES=256 -> res=128, B=2, C=64).
// code = ((b*128 + x/2)*128 + y/2)*128 + z/2  in [0, 4194304)
// Dense histogram + 2-level scan over occupancy flags -> sorted rank per code
// (== jnp.unique inverse). Then exact CSR (counting sort by rank) and a
// gather-mean kernel: one wave per output row, NO feature atomics.

#define RES2 128
#define NCODES (2 * 128 * 128 * 128)   // B * res^3 = 4194304
#define SCAN_BLK 4096                  // NCODES / 1024 codes per block

__global__ void count_codes(const int* __restrict__ coords,
                            unsigned* __restrict__ cnt,
                            int* __restrict__ codes, int n) {
    int i = blockIdx.x * 256 + threadIdx.x;
    if (i >= n) return;
    const int4 v = reinterpret_cast<const int4*>(coords)[i];
    int code = (((v.x * RES2 + (v.y >> 1)) * RES2 + (v.z >> 1)) * RES2) + (v.w >> 1);
    codes[i] = code;
    atomicAdd(&cnt[code], 1u);
}

// Per-block (1024 codes) count of occupied codes.
__global__ void block_flag_sum(const unsigned* __restrict__ cnt,
                               unsigned* __restrict__ btot) {
    __shared__ unsigned sh[256];
    int base = blockIdx.x * 1024 + threadIdx.x * 4;
    const uint4 v = *reinterpret_cast<const uint4*>(cnt + base);
    unsigned s = (v.x != 0) + (v.y != 0) + (v.z != 0) + (v.w != 0);
    sh[threadIdx.x] = s;
    __syncthreads();
    for (int off = 128; off > 0; off >>= 1) {
        if (threadIdx.x < off) sh[threadIdx.x] += sh[threadIdx.x + off];
        __syncthreads();
    }
    if (threadIdx.x == 0) btot[blockIdx.x] = sh[0];
}

// Single block: exclusive scan over the 4096 block totals (4 per thread).
__global__ void scan_block_totals(unsigned* __restrict__ btot) {
    __shared__ unsigned sh[1024];
    int t = threadIdx.x;
    int base = t * 4;
    unsigned v[4], e[4], s = 0;
#pragma unroll
    for (int j = 0; j < 4; ++j) { v[j] = btot[base + j]; e[j] = s; s += v[j]; }
    sh[t] = s;
    __syncthreads();
    for (int off = 1; off < 1024; off <<= 1) {
        unsigned add = (t >= off) ? sh[t - off] : 0u;
        __syncthreads();
        sh[t] += add;
        __syncthreads();
    }
    unsigned excl = (t == 0) ? 0u : sh[t - 1];
#pragma unroll
    for (int j = 0; j < 4; ++j) btot[base + j] = excl + e[j];
}

// Second flag pass: per-block exclusive scan + global base -> sorted rank for
// every occupied code. Writes uniq_code/uniq_cnt; overwrites cnt[code]=rank.
__global__ void scan_write(unsigned* __restrict__ cnt,
                           const unsigned* __restrict__ btot,
                           int* __restrict__ uniq_code,
                           unsigned* __restrict__ uniq_cnt) {
    __shared__ unsigned sh[256];
    int t = threadIdx.x;
    int base = blockIdx.x * 1024 + t * 4;
    const uint4 v = *reinterpret_cast<const uint4*>(cnt + base);
    unsigned c4[4] = {v.x, v.y, v.z, v.w};
    unsigned e[4], s = 0;
#pragma unroll
    for (int j = 0; j < 4; ++j) { e[j] = s; s += (c4[j] != 0); }
    sh[t] = s;
    __syncthreads();
    for (int off = 1; off < 256; off <<= 1) {
        unsigned add = (t >= off) ? sh[t - off] : 0u;
        __syncthreads();
        sh[t] += add;
        __syncthreads();
    }
    unsigned texcl = ((t == 0) ? 0u : sh[t - 1]) + btot[blockIdx.x];
#pragma unroll
    for (int j = 0; j < 4; ++j) {
        if (c4[j]) {
            unsigned r = texcl + e[j];
            uniq_code[r] = base + j;
            uniq_cnt[r] = c4[j];
            cnt[base + j] = r;   // repurpose as rank table
        }
    }
}

// ---- exclusive scan of uniq_cnt (length n) -> row_start ----
__global__ void seg_block_sum(const unsigned* __restrict__ ucnt,
                              unsigned* __restrict__ btot2, int n) {
    __shared__ unsigned sh[256];
    int t = threadIdx.x;
    int base = blockIdx.x * 1024 + t * 4;
    unsigned s = 0;
#pragma unroll
    for (int j = 0; j < 4; ++j) if (base + j < n) s += ucnt[base + j];
    sh[t] = s;
    __syncthreads();
    for (int off = 128; off > 0; off >>= 1) {
        if (t < off) sh[t] += sh[t + off];
        __syncthreads();
    }
    if (t == 0) btot2[blockIdx.x] = sh[0];
}

__global__ void scan_small(unsigned* __restrict__ a, int m) {
    __shared__ unsigned sh[1024];
    int t = threadIdx.x;
    unsigned v = (t < m) ? a[t] : 0u;
    sh[t] = v;
    __syncthreads();
    for (int off = 1; off < 1024; off <<= 1) {
        unsigned add = (t >= off) ? sh[t - off] : 0u;
        __syncthreads();
        sh[t] += add;
        __syncthreads();
    }
    if (t < m) a[t] = sh[t] - v;   // exclusive
}

__global__ void write_row_start(const unsigned* __restrict__ ucnt,
                                const unsigned* __restrict__ btot2,
                                unsigned* __restrict__ row_start, int n) {
    __shared__ unsigned sh[256];
    int t = threadIdx.x;
    int base = blockIdx.x * 1024 + t * 4;
    unsigned v[4], e[4], s = 0;
#pragma unroll
    for (int j = 0; j < 4; ++j) {
        v[j] = (base + j < n) ? ucnt[base + j] : 0u;
        e[j] = s; s += v[j];
    }
    sh[t] = s;
    __syncthreads();
    for (int off = 1; off < 256; off <<= 1) {
        unsigned add = (t >= off) ? sh[t - off] : 0u;
        __syncthreads();
        sh[t] += add;
        __syncthreads();
    }
    unsigned texcl = ((t == 0) ? 0u : sh[t - 1]) + btot2[blockIdx.x];
#pragma unroll
    for (int j = 0; j < 4; ++j)
        if (base + j < n) row_start[base + j] = texcl + e[j];
}

// Counting sort by rank: exact CSR member lists (only 500k tiny atomics).
__global__ void fill_sorted(const int* __restrict__ codes,
                            const unsigned* __restrict__ rank_tab,
                            const unsigned* __restrict__ row_start,
                            unsigned* __restrict__ cursor,
                            int* __restrict__ sorted_idx, int n) {
    int i = blockIdx.x * 256 + threadIdx.x;
    if (i >= n) return;
    unsigned r = rank_tab[codes[i]];
    unsigned pos = atomicAdd(&cursor[r], 1u);
    sorted_idx[row_start[r] + pos] = i;
}

// One wave per output row: gather-mean feats, write coords. No atomics.
__global__ void gather_finalize(const float* __restrict__ feats,
                                const int* __restrict__ sorted_idx,
                                const unsigned* __restrict__ row_start,
                                const unsigned* __restrict__ uniq_cnt,
                                const int* __restrict__ uniq_code,
                                float* __restrict__ outF,
                                float* __restrict__ outC, int n) {
    int tid = blockIdx.x * 256 + threadIdx.x;
    if (tid >= n * 64) return;
    int r = tid >> 6;
    int c = tid & 63;
    unsigned cr = uniq_cnt[r];
    float val = 0.0f;
    if (cr) {
        unsigned st = row_start[r];
        for (unsigned k = 0; k < cr; ++k)
            val += feats[(size_t)sorted_idx[st + k] * 64 + c];
        val /= (float)cr;
    }
    outF[tid] = val;
    if (c < 4) {
        float cv = -1.0f;
        if (cr) {
            int code = uniq_code[r];
            int z = code & 127;
            int y = (code >> 7) & 127;
            int x = (code >> 14) & 127;
            int b = code >> 21;
            cv = (float)((c == 0) ? b : (c == 1) ? x : (c == 2) ? y : z);
        }
        outC[(size_t)r * 4 + c] = cv;
    }
}

extern "C" void kernel_launch(void* const* d_in, const int* in_sizes, int n_in,
                              void* d_out, int out_size, void* d_ws, size_t ws_size,
                              hipStream_t stream) {
    const float* feats = (const float*)d_in[0];
    const int* coords = (const int*)d_in[1];
    const int n = in_sizes[1] / 4;   // N = 500000

    float* outF = (float*)d_out;
    float* outC = outF + (size_t)n * 64;

    unsigned* cnt = (unsigned*)d_ws;                   // NCODES u32 (16.8 MB)
    unsigned* btot = cnt + NCODES;                     // 4096
    unsigned* btot2 = btot + SCAN_BLK;                 // 1024
    int* uniq_code = (int*)(btot2 + 1024);             // n
    unsigned* uniq_cnt = (unsigned*)(uniq_code + n);   // n
    int* codes = (int*)(uniq_cnt + n);                 // n
    unsigned* cursor = (unsigned*)(codes + n);         // n
    unsigned* row_start = cursor + n;                  // n
    int* sorted_idx = (int*)(row_start + n);           // n

    const int nb2 = (n + 1023) / 1024;                 // 489 blocks for n-scan

    hipMemsetAsync(cnt, 0, (size_t)NCODES * sizeof(unsigned), stream);
    hipMemsetAsync(uniq_cnt, 0, (size_t)n * sizeof(unsigned), stream);
    hipMemsetAsync(cursor, 0, (size_t)n * sizeof(unsigned), stream);

    count_codes<<<(n + 255) / 256, 256, 0, stream>>>(coords, cnt, codes, n);
    block_flag_sum<<<SCAN_BLK, 256, 0, stream>>>(cnt, btot);
    scan_block_totals<<<1, 1024, 0, stream>>>(btot);
    scan_write<<<SCAN_BLK, 256, 0, stream>>>(cnt, btot, uniq_code, uniq_cnt);

    seg_block_sum<<<nb2, 256, 0, stream>>>(uniq_cnt, btot2, n);
    scan_small<<<1, 1024, 0, stream>>>(btot2, nb2);
    write_row_start<<<nb2, 256, 0, stream>>>(uniq_cnt, btot2, row_start, n);

    fill_sorted<<<(n + 255) / 256, 256, 0, stream>>>(codes, cnt, row_start, cursor, sorted_idx, n);

    int nc_threads = n * 64;
    gather_finalize<<<(nc_threads + 255) / 256, 256, 0, stream>>>(
        feats, sorted_idx, row_start, uniq_cnt, uniq_code, outF, outC, n);
}

// Round 3
// 168.918 us; speedup vs baseline: 1.6865x; 1.6616x over previous
//
#include <hip/hip_runtime.h>

// Sparse voxel downsample (FACTOR=2, RES=256 -> res=128, B=2, C=64).
// code = ((b*128 + x/2)*128 + y/2)*128 + z/2  in [0, 4194304)
// Dense histogram + 2-level scan over occupancy flags -> sorted rank per code
// (== jnp.unique inverse index, ascending code order, padding at end).
// Hot pass is a scatter: count==1 rows (~94%) are plain stores, count>=2 rows
// are pre-zeroed and receive atomicAdd(v/count) -- no memset(d_out), no
// finalize pass, 3.6M atomics instead of 32M.

#define RES2 128
#define NCODES (2 * 128 * 128 * 128)   // B * res^3 = 4194304
#define SCAN_BLK 4096                  // NCODES / 1024 codes per block

__global__ void count_codes(const int* __restrict__ coords,
                            unsigned* __restrict__ cnt,
                            int* __restrict__ codes, int n) {
    int i = blockIdx.x * 256 + threadIdx.x;
    if (i >= n) return;
    const int4 v = reinterpret_cast<const int4*>(coords)[i];
    int code = (((v.x * RES2 + (v.y >> 1)) * RES2 + (v.z >> 1)) * RES2) + (v.w >> 1);
    codes[i] = code;
    atomicAdd(&cnt[code], 1u);
}

// Per-block (1024 codes) count of occupied codes.
__global__ void block_flag_sum(const unsigned* __restrict__ cnt,
                               unsigned* __restrict__ btot) {
    __shared__ unsigned sh[256];
    int base = blockIdx.x * 1024 + threadIdx.x * 4;
    const uint4 v = *reinterpret_cast<const uint4*>(cnt + base);
    unsigned s = (v.x != 0) + (v.y != 0) + (v.z != 0) + (v.w != 0);
    sh[threadIdx.x] = s;
    __syncthreads();
    for (int off = 128; off > 0; off >>= 1) {
        if (threadIdx.x < off) sh[threadIdx.x] += sh[threadIdx.x + off];
        __syncthreads();
    }
    if (threadIdx.x == 0) btot[blockIdx.x] = sh[0];
}

// Single block: exclusive scan over the 4096 block totals; also writes the
// grand total (n_unique) to *nuq.
__global__ void scan_block_totals(unsigned* __restrict__ btot,
                                  unsigned* __restrict__ nuq) {
    __shared__ unsigned sh[1024];
    int t = threadIdx.x;
    int base = t * 4;
    unsigned v[4], e[4], s = 0;
#pragma unroll
    for (int j = 0; j < 4; ++j) { v[j] = btot[base + j]; e[j] = s; s += v[j]; }
    sh[t] = s;
    __syncthreads();
    for (int off = 1; off < 1024; off <<= 1) {
        unsigned add = (t >= off) ? sh[t - off] : 0u;
        __syncthreads();
        sh[t] += add;
        __syncthreads();
    }
    unsigned excl = (t == 0) ? 0u : sh[t - 1];
#pragma unroll
    for (int j = 0; j < 4; ++j) btot[base + j] = excl + e[j];
    if (t == 1023) *nuq = sh[1023];
}

// Second flag pass: per-block exclusive scan + global base -> sorted rank for
// every occupied code. Overwrites cnt[code] = rank | (count<<19); writes the
// decoded coords for row `rank` directly; zeroes outF rows with count>=2
// (count==1 rows get a plain store in scatter; padding handled by tail_pad).
__global__ void scan_write(unsigned* __restrict__ cnt,
                           const unsigned* __restrict__ btot,
                           float* __restrict__ outF,
                           float* __restrict__ outC) {
    __shared__ unsigned sh[256];
    int t = threadIdx.x;
    int base = blockIdx.x * 1024 + t * 4;
    const uint4 v = *reinterpret_cast<const uint4*>(cnt + base);
    unsigned c4[4] = {v.x, v.y, v.z, v.w};
    unsigned e[4], s = 0;
#pragma unroll
    for (int j = 0; j < 4; ++j) { e[j] = s; s += (c4[j] != 0); }
    sh[t] = s;
    __syncthreads();
    for (int off = 1; off < 256; off <<= 1) {
        unsigned add = (t >= off) ? sh[t - off] : 0u;
        __syncthreads();
        sh[t] += add;
        __syncthreads();
    }
    unsigned texcl = ((t == 0) ? 0u : sh[t - 1]) + btot[blockIdx.x];
#pragma unroll
    for (int j = 0; j < 4; ++j) {
        if (c4[j]) {
            unsigned r = texcl + e[j];
            cnt[base + j] = r | (c4[j] << 19);   // pack rank + count
            int code = base + j;
            int z = code & 127;
            int y = (code >> 7) & 127;
            int x = (code >> 14) & 127;
            int b = code >> 21;
            reinterpret_cast<float4*>(outC)[r] =
                make_float4((float)b, (float)x, (float)y, (float)z);
            if (c4[j] >= 2) {
                float4* row = reinterpret_cast<float4*>(outF + (size_t)r * 64);
                const float4 zz = make_float4(0.f, 0.f, 0.f, 0.f);
#pragma unroll
                for (int q = 0; q < 16; ++q) row[q] = zz;
            }
        }
    }
}

// Padding rows [n_uniq, n): zero feats, coords = -1. One thread per row.
__global__ void tail_pad(const unsigned* __restrict__ nuq,
                         float* __restrict__ outF,
                         float* __restrict__ outC, int n) {
    int r = blockIdx.x * 256 + threadIdx.x;
    if (r >= n) return;
    if (r < (int)*nuq) return;
    float4* row = reinterpret_cast<float4*>(outF + (size_t)r * 64);
    const float4 zz = make_float4(0.f, 0.f, 0.f, 0.f);
#pragma unroll
    for (int q = 0; q < 16; ++q) row[q] = zz;
    reinterpret_cast<float4*>(outC)[r] = make_float4(-1.f, -1.f, -1.f, -1.f);
}

// Hot pass: one wave per input row. Sequential feats read; plain store for
// singleton rows (exact), atomicAdd(v/count) for shared rows (pre-zeroed).
__global__ void scatter(const float* __restrict__ feats,
                        const int* __restrict__ codes,
                        const unsigned* __restrict__ rank_tab,
                        float* __restrict__ outF, int n) {
    int tid = blockIdx.x * 256 + threadIdx.x;
    int i = tid >> 6;
    if (i >= n) return;
    int c = tid & 63;
    unsigned packed = rank_tab[codes[i]];
    unsigned r = packed & 0x7FFFFu;
    unsigned ucnt = packed >> 19;
    float v = feats[tid];
    float* dst = outF + (size_t)r * 64 + c;
    if (ucnt == 1)
        *dst = v;                       // wave-uniform branch
    else
        atomicAdd(dst, v / (float)ucnt);
}

extern "C" void kernel_launch(void* const* d_in, const int* in_sizes, int n_in,
                              void* d_out, int out_size, void* d_ws, size_t ws_size,
                              hipStream_t stream) {
    const float* feats = (const float*)d_in[0];
    const int* coords = (const int*)d_in[1];
    const int n = in_sizes[1] / 4;   // N = 500000

    float* outF = (float*)d_out;
    float* outC = outF + (size_t)n * 64;

    unsigned* cnt = (unsigned*)d_ws;           // NCODES u32 (16.8 MB)
    unsigned* btot = cnt + NCODES;             // 4096
    unsigned* nuq = btot + SCAN_BLK;           // 1
    int* codes = (int*)(nuq + 1);              // n

    hipMemsetAsync(cnt, 0, (size_t)NCODES * sizeof(unsigned), stream);

    count_codes<<<(n + 255) / 256, 256, 0, stream>>>(coords, cnt, codes, n);
    block_flag_sum<<<SCAN_BLK, 256, 0, stream>>>(cnt, btot);
    scan_block_totals<<<1, 1024, 0, stream>>>(btot, nuq);
    scan_write<<<SCAN_BLK, 256, 0, stream>>>(cnt, btot, outF, outC);
    tail_pad<<<(n + 255) / 256, 256, 0, stream>>>(nuq, outF, outC, n);

    int nc_threads = n * 64;
    scatter<<<(nc_threads + 255) / 256, 256, 0, stream>>>(feats, codes, cnt, outF, n);
}

// Round 4
// 133.656 us; speedup vs baseline: 2.1315x; 1.2638x over previous
//
#include <hip/hip_runtime.h>

// Sparse voxel downsample (FACTOR=2, RES=256 -> res=128, B=2, C=64).
// code = ((b*128 + x/2)*128 + y/2)*128 + z/2  in [0, 4194304)
// u8-packed dense histogram + 2-level scan over occupancy flags -> sorted
// rank per code (== jnp.unique inverse, ascending codes, padding at end).
// Hot pass: 8 rows per wave, float4 per lane-quarter; count==1 rows (~94%)
// plain stores, count>=2 rows pre-zeroed + atomicAdd(v/count).

#define RES2 128
#define NCODES (2 * 128 * 128 * 128)   // 4194304 codes
#define NW (NCODES / 4)                // u32 words in u8 histogram
#define HBLK 4096                      // blocks over code space (1024 codes each)

__global__ void count_codes(const int* __restrict__ coords,
                            unsigned* __restrict__ cnt8,
                            int* __restrict__ codes, int n) {
    int i = blockIdx.x * 256 + threadIdx.x;
    if (i >= n) return;
    const int4 v = reinterpret_cast<const int4*>(coords)[i];
    int code = (((v.x * RES2 + (v.y >> 1)) * RES2 + (v.z >> 1)) * RES2) + (v.w >> 1);
    codes[i] = code;
    atomicAdd(&cnt8[code >> 2], 1u << (8 * (code & 3)));   // u8 lanes, max cnt ~9
}

// Per-block (1024 codes = 256 u32 words) count of occupied codes.
__global__ void block_flag_sum(const unsigned* __restrict__ cnt8,
                               unsigned* __restrict__ btot) {
    __shared__ unsigned sh[256];
    int t = threadIdx.x;
    unsigned w = cnt8[blockIdx.x * 256 + t];
    unsigned s = ((w & 0xFFu) != 0) + ((w & 0xFF00u) != 0) +
                 ((w & 0xFF0000u) != 0) + ((w & 0xFF000000u) != 0);
    sh[t] = s;
    __syncthreads();
    for (int off = 128; off > 0; off >>= 1) {
        if (t < off) sh[t] += sh[t + off];
        __syncthreads();
    }
    if (t == 0) btot[blockIdx.x] = sh[0];
}

// Single block: exclusive scan over 4096 block totals; grand total -> *nuq.
__global__ void scan_block_totals(unsigned* __restrict__ btot,
                                  unsigned* __restrict__ nuq) {
    __shared__ unsigned sh[1024];
    int t = threadIdx.x;
    int base = t * 4;
    unsigned v[4], e[4], s = 0;
#pragma unroll
    for (int j = 0; j < 4; ++j) { v[j] = btot[base + j]; e[j] = s; s += v[j]; }
    sh[t] = s;
    __syncthreads();
    for (int off = 1; off < 1024; off <<= 1) {
        unsigned add = (t >= off) ? sh[t - off] : 0u;
        __syncthreads();
        sh[t] += add;
        __syncthreads();
    }
    unsigned excl = (t == 0) ? 0u : sh[t - 1];
#pragma unroll
    for (int j = 0; j < 4; ++j) btot[base + j] = excl + e[j];
    if (t == 1023) *nuq = sh[1023];
}

// Second flag pass: per-block scan + global base -> rank. Writes
// rank_tab[code] = rank | count<<19, decoded coords for row rank, and zeroes
// outF rows with count>=2 (singleton rows are plain-stored by scatter).
__global__ void scan_write(const unsigned* __restrict__ cnt8,
                           const unsigned* __restrict__ btot,
                           unsigned* __restrict__ rank_tab,
                           float* __restrict__ outF,
                           float* __restrict__ outC) {
    __shared__ unsigned sh[256];
    int t = threadIdx.x;
    unsigned w = cnt8[blockIdx.x * 256 + t];
    unsigned c4[4] = {w & 0xFFu, (w >> 8) & 0xFFu, (w >> 16) & 0xFFu, w >> 24};
    unsigned e[4], s = 0;
#pragma unroll
    for (int j = 0; j < 4; ++j) { e[j] = s; s += (c4[j] != 0); }
    sh[t] = s;
    __syncthreads();
    for (int off = 1; off < 256; off <<= 1) {
        unsigned add = (t >= off) ? sh[t - off] : 0u;
        __syncthreads();
        sh[t] += add;
        __syncthreads();
    }
    unsigned texcl = ((t == 0) ? 0u : sh[t - 1]) + btot[blockIdx.x];
    int cbase = (blockIdx.x * 256 + t) * 4;
#pragma unroll
    for (int j = 0; j < 4; ++j) {
        if (c4[j]) {
            unsigned r = texcl + e[j];
            int code = cbase + j;
            rank_tab[code] = r | (c4[j] << 19);
            int z = code & 127;
            int y = (code >> 7) & 127;
            int x = (code >> 14) & 127;
            int b = code >> 21;
            reinterpret_cast<float4*>(outC)[r] =
                make_float4((float)b, (float)x, (float)y, (float)z);
            if (c4[j] >= 2) {
                float4* row = reinterpret_cast<float4*>(outF + (size_t)r * 64);
                const float4 zz = make_float4(0.f, 0.f, 0.f, 0.f);
#pragma unroll
                for (int q = 0; q < 16; ++q) row[q] = zz;
            }
        }
    }
}

// Padding rows [n_uniq, n): zero feats, coords = -1.
__global__ void tail_pad(const unsigned* __restrict__ nuq,
                         float* __restrict__ outF,
                         float* __restrict__ outC, int n) {
    int r = blockIdx.x * 256 + threadIdx.x;
    if (r >= n || r < (int)*nuq) return;
    float4* row = reinterpret_cast<float4*>(outF + (size_t)r * 64);
    const float4 zz = make_float4(0.f, 0.f, 0.f, 0.f);
#pragma unroll
    for (int q = 0; q < 16; ++q) row[q] = zz;
    reinterpret_cast<float4*>(outC)[r] = make_float4(-1.f, -1.f, -1.f, -1.f);
}

// Hot pass: 8 rows per wave. Quarter-wave (16 lanes x float4) = one 256 B row.
// All loads issued before stores -> 8 independent rows in flight per wave.
__global__ void scatter8(const float4* __restrict__ feats4,
                         const int* __restrict__ codes,
                         const unsigned* __restrict__ rank_tab,
                         float4* __restrict__ outF4, int n) {
    int tid = blockIdx.x * 256 + threadIdx.x;
    int lane = threadIdx.x & 63;
    int wave = tid >> 6;
    int q = lane >> 4;
    int sub = lane & 15;
    int ib = wave * 8;
    int i0 = ib + q;
    int i1 = ib + 4 + q;
    if (ib + 7 < n) {   // fast path (always taken for n % 8 == 0)
        int c0 = codes[i0];
        int c1 = codes[i1];
        unsigned p0 = rank_tab[c0];
        unsigned p1 = rank_tab[c1];
        float4 v0 = feats4[(size_t)i0 * 16 + sub];
        float4 v1 = feats4[(size_t)i1 * 16 + sub];
        unsigned r0 = p0 & 0x7FFFFu, u0 = p0 >> 19;
        unsigned r1 = p1 & 0x7FFFFu, u1 = p1 >> 19;
        if (u0 == 1) {
            outF4[(size_t)r0 * 16 + sub] = v0;
        } else {
            float s = 1.0f / (float)u0;
            float* d = (float*)(outF4 + (size_t)r0 * 16 + sub);
            atomicAdd(d + 0, v0.x * s); atomicAdd(d + 1, v0.y * s);
            atomicAdd(d + 2, v0.z * s); atomicAdd(d + 3, v0.w * s);
        }
        if (u1 == 1) {
            outF4[(size_t)r1 * 16 + sub] = v1;
        } else {
            float s = 1.0f / (float)u1;
            float* d = (float*)(outF4 + (size_t)r1 * 16 + sub);
            atomicAdd(d + 0, v1.x * s); atomicAdd(d + 1, v1.y * s);
            atomicAdd(d + 2, v1.z * s); atomicAdd(d + 3, v1.w * s);
        }
    } else {
        for (int h = 0; h < 2; ++h) {
            int i = ib + h * 4 + q;
            if (i >= n) continue;
            int c = codes[i];
            unsigned p = rank_tab[c];
            unsigned r = p & 0x7FFFFu, u = p >> 19;
            float4 v = feats4[(size_t)i * 16 + sub];
            if (u == 1) {
                outF4[(size_t)r * 16 + sub] = v;
            } else {
                float s = 1.0f / (float)u;
                float* d = (float*)(outF4 + (size_t)r * 16 + sub);
                atomicAdd(d + 0, v.x * s); atomicAdd(d + 1, v.y * s);
                atomicAdd(d + 2, v.z * s); atomicAdd(d + 3, v.w * s);
            }
        }
    }
}

extern "C" void kernel_launch(void* const* d_in, const int* in_sizes, int n_in,
                              void* d_out, int out_size, void* d_ws, size_t ws_size,
                              hipStream_t stream) {
    const float* feats = (const float*)d_in[0];
    const int* coords = (const int*)d_in[1];
    const int n = in_sizes[1] / 4;   // N = 500000

    float* outF = (float*)d_out;
    float* outC = outF + (size_t)n * 64;

    unsigned* cnt8 = (unsigned*)d_ws;          // NW u32 (4.19 MB, u8 counts)
    unsigned* btot = cnt8 + NW;                // 4096
    unsigned* nuq = btot + HBLK;               // 1
    int* codes = (int*)(nuq + 1);              // n
    unsigned* rank_tab = (unsigned*)(codes + n);  // NCODES u32 (16.8 MB)

    hipMemsetAsync(cnt8, 0, (size_t)NW * sizeof(unsigned), stream);

    count_codes<<<(n + 255) / 256, 256, 0, stream>>>(coords, cnt8, codes, n);
    block_flag_sum<<<HBLK, 256, 0, stream>>>(cnt8, btot);
    scan_block_totals<<<1, 1024, 0, stream>>>(btot, nuq);
    scan_write<<<HBLK, 256, 0, stream>>>(cnt8, btot, rank_tab, outF, outC);
    tail_pad<<<(n + 255) / 256, 256, 0, stream>>>(nuq, outF, outC, n);

    int waves = (n + 7) / 8;
    int blocks = (waves * 64 + 255) / 256;
    scatter8<<<blocks, 256, 0, stream>>>((const float4*)feats, codes,
                                         rank_tab, (float4*)outF, n);
}

// Round 5
// 125.641 us; speedup vs baseline: 2.2674x; 1.0638x over previous
//
#include <hip/hip_runtime.h>

// Sparse voxel downsample (FACTOR=2, RES=256 -> res=128, B=2, C=64).
// code = ((b*128 + x/2)*128 + y/2)*128 + z/2  in [0, 4194304)
// u8 dense histogram + 2-level packed (flag,count) scan -> sorted rank AND
// row_start per unique code (== jnp.unique order). Counting-sort the INDICES
// by rank, then a gather hot pass: sequential writes, random 256B reads with
// 4 chains in flight per wave, in-register mean (no feature atomics).

#define RES2 128
#define NCODES (2 * 128 * 128 * 128)   // 4194304 codes
#define NW (NCODES / 4)                // u32 words in u8 histogram
#define HBLK 4096                      // blocks over code space (1024 codes)

typedef unsigned long long u64;

__global__ void count_codes(const int* __restrict__ coords,
                            unsigned* __restrict__ cnt8,
                            int* __restrict__ codes, int n) {
    int i = blockIdx.x * 256 + threadIdx.x;
    if (i >= n) return;
    const int4 v = reinterpret_cast<const int4*>(coords)[i];
    int code = (((v.x * RES2 + (v.y >> 1)) * RES2 + (v.z >> 1)) * RES2) + (v.w >> 1);
    codes[i] = code;
    atomicAdd(&cnt8[code >> 2], 1u << (8 * (code & 3)));   // u8 lanes, max ~9
}

// Per block of 1024 codes: packed (count_sum<<32 | flag_sum).
__global__ void block_sums(const unsigned* __restrict__ cnt8,
                           u64* __restrict__ btot) {
    __shared__ u64 sh[256];
    int t = threadIdx.x;
    unsigned w = cnt8[blockIdx.x * 256 + t];
    unsigned c0 = w & 0xFFu, c1 = (w >> 8) & 0xFFu,
             c2 = (w >> 16) & 0xFFu, c3 = w >> 24;
    u64 s = ((u64)(c0 + c1 + c2 + c3) << 32) |
            (u64)((c0 != 0) + (c1 != 0) + (c2 != 0) + (c3 != 0));
    sh[t] = s;
    __syncthreads();
    for (int off = 128; off > 0; off >>= 1) {
        if (t < off) sh[t] += sh[t + off];
        __syncthreads();
    }
    if (t == 0) btot[blockIdx.x] = sh[0];
}

// Single block: exclusive scan over 4096 packed totals; n_unique -> *nuq.
__global__ void scan_totals(u64* __restrict__ btot, unsigned* __restrict__ nuq) {
    __shared__ u64 sh[1024];
    int t = threadIdx.x;
    int base = t * 4;
    u64 v[4], e[4], s = 0;
#pragma unroll
    for (int j = 0; j < 4; ++j) { v[j] = btot[base + j]; e[j] = s; s += v[j]; }
    sh[t] = s;
    __syncthreads();
    for (int off = 1; off < 1024; off <<= 1) {
        u64 add = (t >= off) ? sh[t - off] : 0ull;
        __syncthreads();
        sh[t] += add;
        __syncthreads();
    }
    u64 excl = (t == 0) ? 0ull : sh[t - 1];
#pragma unroll
    for (int j = 0; j < 4; ++j) btot[base + j] = excl + e[j];
    if (t == 1023) *nuq = (unsigned)(sh[1023] & 0xFFFFFFFFull);
}

// Second pass: per-block packed scan + base -> for each occupied code:
// rank_tab[code] = rank;  uniq_cc[rank] = code | cnt<<22;
// row_end[rank] = row_start (fill pass increments it to row_end).
__global__ void scan_write(const unsigned* __restrict__ cnt8,
                           const u64* __restrict__ btot,
                           unsigned* __restrict__ rank_tab,
                           unsigned* __restrict__ uniq_cc,
                           unsigned* __restrict__ row_end) {
    __shared__ u64 sh[256];
    int t = threadIdx.x;
    unsigned w = cnt8[blockIdx.x * 256 + t];
    unsigned c4[4] = {w & 0xFFu, (w >> 8) & 0xFFu, (w >> 16) & 0xFFu, w >> 24};
    u64 e[4], s = 0;
#pragma unroll
    for (int j = 0; j < 4; ++j) {
        e[j] = s;
        s += ((u64)c4[j] << 32) | (u64)(c4[j] != 0);
    }
    sh[t] = s;
    __syncthreads();
    for (int off = 1; off < 256; off <<= 1) {
        u64 add = (t >= off) ? sh[t - off] : 0ull;
        __syncthreads();
        sh[t] += add;
        __syncthreads();
    }
    u64 texcl = ((t == 0) ? 0ull : sh[t - 1]) + btot[blockIdx.x];
    int cbase = (blockIdx.x * 256 + t) * 4;
#pragma unroll
    for (int j = 0; j < 4; ++j) {
        if (c4[j]) {
            unsigned r = (unsigned)((texcl + e[j]) & 0xFFFFFFFFull);
            unsigned st = (unsigned)((texcl + e[j]) >> 32);
            int code = cbase + j;
            rank_tab[code] = r;
            uniq_cc[r] = (unsigned)code | (c4[j] << 22);
            row_end[r] = st;
        }
    }
}

// Counting sort of indices by rank. After this, row_end[r] = start+cnt.
__global__ void fill_sorted(const int* __restrict__ codes,
                            const unsigned* __restrict__ rank_tab,
                            unsigned* __restrict__ row_end,
                            int* __restrict__ sorted_idx, int n) {
    int i = blockIdx.x * 256 + threadIdx.x;
    if (i >= n) return;
    unsigned r = rank_tab[codes[i]];
    unsigned pos = atomicAdd(&row_end[r], 1u);
    sorted_idx[pos] = i;
}

// Hot pass: 16 output rows per wave (quarter-wave = one 256B row, 4 batches
// with independent load chains). Sequential writes; random 256B feat reads.
__global__ void gather16(const float4* __restrict__ feats4,
                         const int* __restrict__ sorted_idx,
                         const unsigned* __restrict__ row_end,
                         const unsigned* __restrict__ uniq_cc,
                         const unsigned* __restrict__ nuq_p,
                         float4* __restrict__ outF4,
                         float4* __restrict__ outC4, int n) {
    int tid = blockIdx.x * 256 + threadIdx.x;
    int wave = tid >> 6;
    int lane = threadIdx.x & 63;
    int q = lane >> 4;
    int sub = lane & 15;
    int rb = wave * 16 + q;
    int nuq = (int)*nuq_p;

    int r[4];
    bool ok[4];
#pragma unroll
    for (int k = 0; k < 4; ++k) { r[k] = rb + k * 4; ok[k] = (r[k] < nuq); }

    bool allv = (wave * 16 + 15 < n) & ok[0] & ok[1] & ok[2] & ok[3];
    if (allv) {
        unsigned en[4], cc[4];
#pragma unroll
        for (int k = 0; k < 4; ++k) en[k] = row_end[r[k]];
#pragma unroll
        for (int k = 0; k < 4; ++k) cc[k] = uniq_cc[r[k]];
        int cnt[4], st[4], i0[4];
#pragma unroll
        for (int k = 0; k < 4; ++k) {
            cnt[k] = (int)(cc[k] >> 22);
            st[k] = (int)en[k] - cnt[k];
        }
#pragma unroll
        for (int k = 0; k < 4; ++k) i0[k] = sorted_idx[st[k]];
        float4 a[4];
#pragma unroll
        for (int k = 0; k < 4; ++k) a[k] = feats4[(size_t)i0[k] * 16 + sub];
#pragma unroll
        for (int k = 0; k < 4; ++k) {
            if (cnt[k] > 1) {
                for (int m = 1; m < cnt[k]; ++m) {
                    int i = sorted_idx[st[k] + m];
                    float4 v = feats4[(size_t)i * 16 + sub];
                    a[k].x += v.x; a[k].y += v.y; a[k].z += v.z; a[k].w += v.w;
                }
                float sc = 1.0f / (float)cnt[k];
                a[k].x *= sc; a[k].y *= sc; a[k].z *= sc; a[k].w *= sc;
            }
            outF4[(size_t)r[k] * 16 + sub] = a[k];
            if (sub == 0) {
                unsigned code = cc[k] & 0x3FFFFFu;
                outC4[r[k]] = make_float4((float)(code >> 21),
                                          (float)((code >> 14) & 127),
                                          (float)((code >> 7) & 127),
                                          (float)(code & 127));
            }
        }
    } else {
#pragma unroll
        for (int k = 0; k < 4; ++k) {
            if (r[k] >= n) continue;
            if (ok[k]) {
                unsigned en = row_end[r[k]];
                unsigned cc = uniq_cc[r[k]];
                int cnt = (int)(cc >> 22);
                int st = (int)en - cnt;
                float4 a = make_float4(0.f, 0.f, 0.f, 0.f);
                for (int m = 0; m < cnt; ++m) {
                    int i = sorted_idx[st + m];
                    float4 v = feats4[(size_t)i * 16 + sub];
                    a.x += v.x; a.y += v.y; a.z += v.z; a.w += v.w;
                }
                float sc = 1.0f / (float)cnt;
                a.x *= sc; a.y *= sc; a.z *= sc; a.w *= sc;
                outF4[(size_t)r[k] * 16 + sub] = a;
                if (sub == 0) {
                    unsigned code = cc & 0x3FFFFFu;
                    outC4[r[k]] = make_float4((float)(code >> 21),
                                              (float)((code >> 14) & 127),
                                              (float)((code >> 7) & 127),
                                              (float)(code & 127));
                }
            } else {
                outF4[(size_t)r[k] * 16 + sub] = make_float4(0.f, 0.f, 0.f, 0.f);
                if (sub == 0)
                    outC4[r[k]] = make_float4(-1.f, -1.f, -1.f, -1.f);
            }
        }
    }
}

extern "C" void kernel_launch(void* const* d_in, const int* in_sizes, int n_in,
                              void* d_out, int out_size, void* d_ws, size_t ws_size,
                              hipStream_t stream) {
    const float* feats = (const float*)d_in[0];
    const int* coords = (const int*)d_in[1];
    const int n = in_sizes[1] / 4;   // N = 500000

    float* outF = (float*)d_out;
    float4* outC4 = (float4*)(outF + (size_t)n * 64);

    unsigned* cnt8 = (unsigned*)d_ws;              // NW u32 (4.19 MB)
    u64* btot = (u64*)(cnt8 + NW);                 // 4096 u64
    unsigned* nuq = (unsigned*)(btot + HBLK);      // 1 (+1 pad)
    int* codes = (int*)(nuq + 2);                  // n
    unsigned* rank_tab = (unsigned*)(codes + n);   // NCODES u32 (16.8 MB)
    unsigned* uniq_cc = rank_tab + NCODES;         // n
    unsigned* row_end = uniq_cc + n;               // n
    int* sorted_idx = (int*)(row_end + n);         // n

    hipMemsetAsync(cnt8, 0, (size_t)NW * sizeof(unsigned), stream);

    count_codes<<<(n + 255) / 256, 256, 0, stream>>>(coords, cnt8, codes, n);
    block_sums<<<HBLK, 256, 0, stream>>>(cnt8, btot);
    scan_totals<<<1, 1024, 0, stream>>>(btot, nuq);
    scan_write<<<HBLK, 256, 0, stream>>>(cnt8, btot, rank_tab, uniq_cc, row_end);
    fill_sorted<<<(n + 255) / 256, 256, 0, stream>>>(codes, rank_tab, row_end, sorted_idx, n);

    int waves = (n + 15) / 16;
    int blocks = (waves * 64 + 255) / 256;
    gather16<<<blocks, 256, 0, stream>>>((const float4*)feats, sorted_idx,
                                         row_end, uniq_cc, nuq,
                                         (float4*)outF, outC4, n);
}